// Round 1
// 459.257 us; speedup vs baseline: 1.0652x; 1.0652x over previous
//
#include <hip/hip_runtime.h>
#include <hip/hip_bf16.h>

// Shapes
#define B_   128
#define S_   400
#define H_   512
#define V_   50257
#define VX_  50307

// Output offsets (floats, concatenated in return order)
#define OFF_FINAL 0
#define OFF_PGEN  6439296
#define OFF_ATTN  6439424
#define OFF_COV   6490624
#define OFF_H1    6541824
#define OFF_C1    6607360
#define OFF_DEC   6672896

typedef __attribute__((ext_vector_type(8))) short bf16x8;
typedef __attribute__((ext_vector_type(4))) float f32x4;

static __device__ __forceinline__ float sigmoid_f(float x) {
    return 1.0f / (1.0f + __expf(-x));
}
static __device__ __forceinline__ float tanh_f(float x) {
    return 1.0f - 2.0f / (__expf(2.0f * x) + 1.0f);
}
// f32x2 -> packed bf16x2 (RNE) — v_cvt_pk_bf16_f32 on gfx950
static __device__ __forceinline__ unsigned int pk2(float x, float y) {
    union { __hip_bfloat162 h; unsigned int u; } cv;
    cv.h = __float22bfloat162_rn(make_float2(x, y));
    return cv.u;
}

// Zero the split-K accumulation region of ws (w_x, w_decfea, w_gates, w_pga
// laid out contiguously: 393344 floats = 98336 float4) + o_dec (16384 float4).
__global__ __launch_bounds__(256) void zero_ws(
    float4* __restrict__ ws4, float4* __restrict__ dec4)
{
    const int i = blockIdx.x * 256 + threadIdx.x;
    const float4 z = make_float4(0.f, 0.f, 0.f, 0.f);
    if (i < 98336) ws4[i] = z;
    if (i < 16384) dec4[i] = z;
}

// ---------------------------------------------------------------------------
// C[128 x N] (+)= A1[128x512] @ W1^T + (A2 ? A2[128x512] @ W2^T : 0) + bias1
// Split-K: grid.y = K-chunks; chunk c covers kg in [c*KC, (c+1)*KC), KC=Ktot/chunks.
// gridDim.y>1 -> atomicAdd epilogue into pre-zeroed C (bias added by chunk 0);
// gridDim.y==1 -> direct store. Optional fused p_gen partial dot (wpg != null).
// Optional fused per-block row softmax stats (pm/ps != null, gridDim.y==1):
// pm[m*gridDim.x+bx] = max over the block's 64-col tile, ps = exp-sum vs that max.
// bf16 MFMA 16x16x32, tile M=128 x N=NT*16, BK=32, 256 thr, reg-prefetch pipeline.
// ---------------------------------------------------------------------------
template <int NT>
__global__ __launch_bounds__(256) void gemm_mfma(
    const float* __restrict__ A1, const float* __restrict__ W1, int ldw1, int kwo1,
    const float* __restrict__ A2, const float* __restrict__ W2, int ldw2, int kwo2,
    const float* __restrict__ bias1,
    float* __restrict__ C, int N,
    const float* __restrict__ wpg, float* __restrict__ pgen_acc,
    float* __restrict__ pm, float* __restrict__ ps)
{
    __shared__ __align__(16) unsigned short As[128 * 40];
    __shared__ __align__(16) unsigned short Ws[NT * 16 * 40];
    const int tid  = threadIdx.x;
    const int bn0  = blockIdx.x * (NT * 16);
    const int lane = tid & 63;
    const int wv   = tid >> 6;
    const int quad = lane >> 4;
    const int col  = lane & 15;

    f32x4 acc[2][NT];
#pragma unroll
    for (int i = 0; i < 2; ++i)
#pragma unroll
        for (int j = 0; j < NT; ++j) acc[i][j] = (f32x4){0.f, 0.f, 0.f, 0.f};

    const int ar = tid >> 1;
    const int ac = (tid & 1) << 4;
    const int wr = (NT == 8) ? (tid >> 1) : (tid >> 2);
    const int wc = (NT == 8) ? ((tid & 1) << 4) : ((tid & 3) << 3);
    const int wrg = (bn0 + wr < N) ? (bn0 + wr) : (N - 1);

    const int Ktot = (A2 != nullptr) ? 1024 : 512;
    const int KC   = Ktot / gridDim.y;
    const int kg0  = blockIdx.y * KC;
    const int nsteps = KC >> 5;

    const float* ApB[2];
    const float* WpB[2];
    ApB[0] = A1 + (long)ar * 512 + ac;
    WpB[0] = W1 + (long)wrg * ldw1 + kwo1 + wc;
    ApB[1] = A2 ? (A2 + (long)ar * 512 + ac) : ApB[0];
    WpB[1] = W2 ? (W2 + (long)wrg * ldw2 + kwo2 + wc) : WpB[0];

    float4 aC[4], wC[NT / 2], aN[4], wN[NT / 2];

    auto fetch = [&](int s, float4* a, float4* w) {
        const int kg = kg0 + (s << 5);
        const int ph = kg >> 9;
        const int k0 = kg & 511;
        const float* Ap = ApB[ph] + k0;
        const float* Wp = WpB[ph] + k0;
#pragma unroll
        for (int i = 0; i < 4; ++i) a[i] = *(const float4*)(Ap + i * 4);
#pragma unroll
        for (int i = 0; i < NT / 2; ++i) w[i] = *(const float4*)(Wp + i * 4);
    };

    fetch(0, aC, wC);
    for (int s = 0; s < nsteps; ++s) {
        __syncthreads();
        uint4* apd = (uint4*)&As[ar * 40 + ac];
        apd[0] = make_uint4(pk2(aC[0].x, aC[0].y), pk2(aC[0].z, aC[0].w),
                            pk2(aC[1].x, aC[1].y), pk2(aC[1].z, aC[1].w));
        apd[1] = make_uint4(pk2(aC[2].x, aC[2].y), pk2(aC[2].z, aC[2].w),
                            pk2(aC[3].x, aC[3].y), pk2(aC[3].z, aC[3].w));
        uint4* wpd = (uint4*)&Ws[wr * 40 + wc];
        wpd[0] = make_uint4(pk2(wC[0].x, wC[0].y), pk2(wC[0].z, wC[0].w),
                            pk2(wC[1].x, wC[1].y), pk2(wC[1].z, wC[1].w));
        if (NT == 8)
            wpd[1] = make_uint4(pk2(wC[2].x, wC[2].y), pk2(wC[2].z, wC[2].w),
                                pk2(wC[3].x, wC[3].y), pk2(wC[3].z, wC[3].w));
        __syncthreads();

        if (s + 1 < nsteps) fetch(s + 1, aN, wN);

        const bf16x8 aF0 = *(const bf16x8*)&As[(wv * 32 + col) * 40 + quad * 8];
        const bf16x8 aF1 = *(const bf16x8*)&As[(wv * 32 + 16 + col) * 40 + quad * 8];
#pragma unroll
        for (int ni = 0; ni < NT; ++ni) {
            const bf16x8 bF = *(const bf16x8*)&Ws[(ni * 16 + col) * 40 + quad * 8];
            acc[0][ni] = __builtin_amdgcn_mfma_f32_16x16x32_bf16(aF0, bF, acc[0][ni], 0, 0, 0);
            acc[1][ni] = __builtin_amdgcn_mfma_f32_16x16x32_bf16(aF1, bF, acc[1][ni], 0, 0, 0);
        }
#pragma unroll
        for (int i = 0; i < 4; ++i) aC[i] = aN[i];
#pragma unroll
        for (int i = 0; i < NT / 2; ++i) wC[i] = wN[i];
    }

    const bool split = (gridDim.y > 1);
    const bool addb  = (!split) || (blockIdx.y == 0);

    // Fused per-block row-softmax partials (vocab GEMM): per row of this
    // block's 64-col tile, tile-max and exp-sum vs tile-max.
    if (pm != nullptr) {
#pragma unroll
        for (int mi = 0; mi < 2; ++mi) {
#pragma unroll
            for (int r = 0; r < 4; ++r) {
                float vv[NT];
                float mx = -3.0e38f;
#pragma unroll
                for (int ni = 0; ni < NT; ++ni) {
                    const int n = bn0 + ni * 16 + col;
                    vv[ni] = (n < N) ? (acc[mi][ni][r] + bias1[n]) : -3.0e38f;
                    mx = fmaxf(mx, vv[ni]);
                }
                mx = fmaxf(mx, __shfl_xor(mx, 1));
                mx = fmaxf(mx, __shfl_xor(mx, 2));
                mx = fmaxf(mx, __shfl_xor(mx, 4));
                mx = fmaxf(mx, __shfl_xor(mx, 8));
                float sum = 0.f;
#pragma unroll
                for (int ni = 0; ni < NT; ++ni) sum += __expf(vv[ni] - mx);
                sum += __shfl_xor(sum, 1);
                sum += __shfl_xor(sum, 2);
                sum += __shfl_xor(sum, 4);
                sum += __shfl_xor(sum, 8);
                if (col == 0) {
                    const int m = wv * 32 + mi * 16 + quad * 4 + r;
                    pm[(long)m * gridDim.x + blockIdx.x] = mx;
                    ps[(long)m * gridDim.x + blockIdx.x] = sum;
                }
            }
        }
    }

    float pgp[2][4];
#pragma unroll
    for (int i = 0; i < 2; ++i)
#pragma unroll
        for (int r = 0; r < 4; ++r) pgp[i][r] = 0.f;

#pragma unroll
    for (int mi = 0; mi < 2; ++mi) {
#pragma unroll
        for (int ni = 0; ni < NT; ++ni) {
            const int n = bn0 + ni * 16 + col;
            if (n < N) {
                const float bv = addb ? bias1[n] : 0.f;
                const float wpv = wpg ? wpg[n] : 0.f;
#pragma unroll
                for (int r = 0; r < 4; ++r) {
                    const int m = wv * 32 + mi * 16 + quad * 4 + r;
                    const float v = acc[mi][ni][r] + bv;
                    if (split) atomicAdd(&C[(long)m * N + n], v);
                    else       C[(long)m * N + n] = v;
                    pgp[mi][r] += v * wpv;
                }
            }
        }
    }
    if (wpg) {
        // reduce over the 16 col-lanes of each quad, then one atomic per row
#pragma unroll
        for (int mi = 0; mi < 2; ++mi)
#pragma unroll
            for (int r = 0; r < 4; ++r) {
                float v = pgp[mi][r];
                v += __shfl_xor(v, 1); v += __shfl_xor(v, 2);
                v += __shfl_xor(v, 4); v += __shfl_xor(v, 8);
                if (col == 0) {
                    const int m = wv * 32 + mi * 16 + quad * 4 + r;
                    atomicAdd(&pgen_acc[m], v);
                }
            }
    }
}

// Elementwise LSTM cell over the accumulated gates buffer [128 x 2048]
// (i,f,g,o column-stacked). b_ih was added by the gates GEMM; add b_hh here.
__global__ __launch_bounds__(256) void lstm_cell(
    const float* __restrict__ gates, const float* __restrict__ bhh,
    const float* __restrict__ c0,
    float* __restrict__ h1, float* __restrict__ c1)
{
    const int idx = blockIdx.x * 256 + threadIdx.x;  // 65536 = 128*512
    const int m = idx >> 9;
    const int h = idx & 511;
    const float* g = gates + (long)m * 2048;
    const float iv = sigmoid_f(g[h]        + bhh[h]);
    const float fv = sigmoid_f(g[512 + h]  + bhh[512 + h]);
    const float gv = tanh_f   (g[1024 + h] + bhh[1024 + h]);
    const float ov = sigmoid_f(g[1536 + h] + bhh[1536 + h]);
    const float c = fv * c0[idx] + iv * gv;
    c1[idx] = c;
    h1[idx] = ov * tanh_f(c);
}

// e[b,s] = sum_h tanh(sf[b,s,h] + dec_fea[b,h] + wc*cov[b,s]) * v_att[h]
__global__ __launch_bounds__(256) void attn_scores(
    const float* __restrict__ sfeat, const float* __restrict__ decfea,
    const float* __restrict__ cov, const float* __restrict__ wc,
    const float* __restrict__ vatt, float* __restrict__ e)
{
    const int lane = threadIdx.x & 63;
    const int pair = blockIdx.x * 4 + (threadIdx.x >> 6);  // b*400+s
    const int b = pair / 400;
    const float cc = wc[0] * cov[pair];
    const float* sp = sfeat + ((long)pair << 9) + (lane << 3);
    const float* dp = decfea + (b << 9) + (lane << 3);
    const float* vp = vatt + (lane << 3);
    const float4 s0 = *(const float4*)sp, s1 = *(const float4*)(sp + 4);
    const float4 d0 = *(const float4*)dp, d1 = *(const float4*)(dp + 4);
    const float4 v0 = *(const float4*)vp, v1 = *(const float4*)(vp + 4);
    float acc = tanh_f(s0.x + d0.x + cc) * v0.x
              + tanh_f(s0.y + d0.y + cc) * v0.y
              + tanh_f(s0.z + d0.z + cc) * v0.z
              + tanh_f(s0.w + d0.w + cc) * v0.w
              + tanh_f(s1.x + d1.x + cc) * v1.x
              + tanh_f(s1.y + d1.y + cc) * v1.y
              + tanh_f(s1.z + d1.z + cc) * v1.z
              + tanh_f(s1.w + d1.w + cc) * v1.w;
#pragma unroll
    for (int off = 32; off > 0; off >>= 1) acc += __shfl_down(acc, off);
    if (lane == 0) e[pair] = acc;
}

// Masked softmax over S per batch row + coverage update; also zeroes ctx accum.
__global__ __launch_bounds__(256) void attn_softmax(
    const float* __restrict__ e, const float* __restrict__ mask,
    const float* __restrict__ cov,
    float* __restrict__ attn, float* __restrict__ covnew, float* __restrict__ ctx)
{
    __shared__ float sm[4], sps[4], spms[4];
    const int b = blockIdx.x, tid = threadIdx.x;
    ctx[(b << 9) + tid] = 0.f;
    ctx[(b << 9) + 256 + tid] = 0.f;

    float vals[2], msk[2];
    float m = -3.0e38f;
#pragma unroll
    for (int it = 0; it < 2; ++it) {
        const int s = tid + (it << 8);
        float mk = 0.f, v = -3.0e38f;
        if (s < 400) {
            mk = mask[b * 400 + s];
            v = (mk > 0.f) ? e[b * 400 + s] : -1.0e9f;
        }
        vals[it] = v; msk[it] = mk;
        m = fmaxf(m, v);
    }
#pragma unroll
    for (int off = 32; off > 0; off >>= 1) m = fmaxf(m, __shfl_down(m, off));
    if ((tid & 63) == 0) sm[tid >> 6] = m;
    __syncthreads();
    const float M = fmaxf(fmaxf(sm[0], sm[1]), fmaxf(sm[2], sm[3]));

    float p[2], sp = 0.f, spm = 0.f;
#pragma unroll
    for (int it = 0; it < 2; ++it) {
        const int s = tid + (it << 8);
        float pv = 0.f;
        if (s < 400) pv = __expf(vals[it] - M);
        p[it] = pv; sp += pv; spm += pv * msk[it];
    }
#pragma unroll
    for (int off = 32; off > 0; off >>= 1) {
        sp += __shfl_down(sp, off);
        spm += __shfl_down(spm, off);
    }
    if ((tid & 63) == 0) { sps[tid >> 6] = sp; spms[tid >> 6] = spm; }
    __syncthreads();
    const float SP = sps[0] + sps[1] + sps[2] + sps[3];
    const float SPM = spms[0] + spms[1] + spms[2] + spms[3];
    const float inv = 1.0f / (SPM + 1e-12f * SP);
#pragma unroll
    for (int it = 0; it < 2; ++it) {
        const int s = tid + (it << 8);
        if (s < 400) {
            const float a = p[it] * msk[it] * inv;
            attn[b * 400 + s] = a;
            covnew[b * 400 + s] = cov[b * 400 + s] + a;
        }
    }
}

// ctx[b,h] += sum over an s-chunk of attn[b,s]*states[b,s,h]; 4 chunks per b
__global__ __launch_bounds__(256) void ctx_kernel(
    const float* __restrict__ attn, const float* __restrict__ states,
    float* __restrict__ ctx)
{
    const int bx = blockIdx.x;  // 512
    const int b = bx >> 2, chunk = bx & 3;
    const int tid = threadIdx.x;
    const int c = tid & 127;
    const int sh = tid >> 7;
    const int s0 = chunk * 100 + sh;
    const float* base = states + (long)b * 400 * 512;
    float4 acc = make_float4(0.f, 0.f, 0.f, 0.f);
    for (int i = 0; i < 50; ++i) {
        const int s = s0 + (i << 1);
        const float a = attn[b * 400 + s];
        const float4 st = *(const float4*)(base + (long)s * 512 + (c << 2));
        acc.x = fmaf(a, st.x, acc.x);
        acc.y = fmaf(a, st.y, acc.y);
        acc.z = fmaf(a, st.z, acc.z);
        acc.w = fmaf(a, st.w, acc.w);
    }
    float* cp = ctx + (b << 9) + (c << 2);
    atomicAdd(cp + 0, acc.x);
    atomicAdd(cp + 1, acc.y);
    atomicAdd(cp + 2, acc.z);
    atomicAdd(cp + 3, acc.w);
}

// final[b, v<V] = p_gen*softmax(logits); final[b, V..VEXT) = 0.
// Merges the nblk per-tile row-stat partials (written by the vocab GEMM
// epilogue); computes p_gen from the fused accumulator; block (0,b) writes o_pgen.
__global__ __launch_bounds__(256) void final_write(
    const float* __restrict__ logits, const float* __restrict__ pm,
    const float* __restrict__ ps, const float* __restrict__ pgen_acc,
    const float* __restrict__ bpg, float* __restrict__ final,
    float* __restrict__ o_pgen, int nblk)
{
    __shared__ float sred[4];
    __shared__ float sM, sS;
    const int b = blockIdx.y;
    const int tid = threadIdx.x;
    const float* pmb = pm + (long)b * nblk;
    const float* psb = ps + (long)b * nblk;

    float m = -3.0e38f;
    for (int i = tid; i < nblk; i += 256) m = fmaxf(m, pmb[i]);
#pragma unroll
    for (int off = 32; off > 0; off >>= 1) m = fmaxf(m, __shfl_down(m, off));
    if ((tid & 63) == 0) sred[tid >> 6] = m;
    __syncthreads();
    if (tid == 0) sM = fmaxf(fmaxf(sred[0], sred[1]), fmaxf(sred[2], sred[3]));
    __syncthreads();
    const float M = sM;

    float s = 0.f;
    for (int i = tid; i < nblk; i += 256) s += psb[i] * __expf(pmb[i] - M);
#pragma unroll
    for (int off = 32; off > 0; off >>= 1) s += __shfl_down(s, off);
    if ((tid & 63) == 0) sred[tid >> 6] = s;
    __syncthreads();
    if (tid == 0) sS = sred[0] + sred[1] + sred[2] + sred[3];
    __syncthreads();
    const float S = sS;

    const float pg = sigmoid_f(pgen_acc[b] + bpg[0]);
    if (blockIdx.x == 0 && tid == 0) o_pgen[b] = pg;

    const int v0 = (blockIdx.x * 256 + tid) << 2;
    if (v0 >= VX_) return;
    const float sc = pg / S;
    const float* row = logits + (long)b * V_;
    float* out = final + (long)b * VX_ + v0;
#pragma unroll
    for (int j = 0; j < 4; ++j) {
        const int v = v0 + j;
        if (v < VX_) out[j] = (v < V_) ? __expf(row[v] - M) * sc : 0.f;
    }
}

// scatter-add copy distribution
__global__ __launch_bounds__(256) void scatter_kernel(
    const int* __restrict__ ids, const float* __restrict__ attn,
    const float* __restrict__ pgen, float* __restrict__ final)
{
    const int s = blockIdx.x * 256 + threadIdx.x;
    const int b = blockIdx.y;
    if (s < 400) {
        const float v = (1.0f - pgen[b]) * attn[b * 400 + s];
        atomicAdd(final + (long)b * VX_ + ids[b * 400 + s], v);
    }
}

extern "C" void kernel_launch(void* const* d_in, const int* in_sizes, int n_in,
                              void* d_out, int out_size, void* d_ws, size_t ws_size,
                              hipStream_t stream)
{
    const float* input_emb  = (const float*)d_in[0];
    const float* input_feed = (const float*)d_in[1];
    const float* hidden     = (const float*)d_in[2];
    const float* context    = (const float*)d_in[3];
    const float* states     = (const float*)d_in[4];
    const float* sfeat      = (const float*)d_in[5];
    const float* mask       = (const float*)d_in[6];
    const float* cov        = (const float*)d_in[7];
    const int*   src_ids    = (const int*)d_in[8];
    const float* W_ic  = (const float*)d_in[9];
    const float* b_ic  = (const float*)d_in[10];
    const float* W_ih  = (const float*)d_in[11];
    const float* W_hh  = (const float*)d_in[12];
    const float* b_ih  = (const float*)d_in[13];
    const float* b_hh  = (const float*)d_in[14];
    const float* W_dec = (const float*)d_in[15];
    const float* b_att = (const float*)d_in[16];
    const float* v_att = (const float*)d_in[17];
    const float* w_c   = (const float*)d_in[18];
    const float* W_out = (const float*)d_in[19];
    const float* b_out = (const float*)d_in[20];
    const float* W_pg  = (const float*)d_in[21];
    const float* b_pg  = (const float*)d_in[22];
    const float* W_v   = (const float*)d_in[23];
    const float* b_v   = (const float*)d_in[24];

    float* out = (float*)d_out;
    float* o_final = out + OFF_FINAL;
    float* o_pgen  = out + OFF_PGEN;
    float* o_attn  = out + OFF_ATTN;
    float* o_cov   = out + OFF_COV;
    float* o_h1    = out + OFF_H1;
    float* o_c1    = out + OFF_C1;
    float* o_dec   = out + OFF_DEC;

    // ws layout (floats). [0, 393344) is the zeroed split-K accumulation region.
    float* ws = (float*)d_ws;
    float* w_x      = ws;            // 65536   (128x512)
    float* w_decfea = ws + 65536;    // 65536   (128x512)
    float* w_gates  = ws + 131072;   // 262144  (128x2048)
    float* w_pga    = ws + 393216;   // 128
    float* w_e      = ws + 393344;   // 51200   (128x400)
    float* w_ctx    = ws + 444544;   // 65536   (128x512)
    float* w_logits = ws + 510080;   // 6432896 (128x50257)
    float* w_pm     = ws + 6942976;  // 100608  (128x786)
    float* w_ps     = ws + 7043584;  // 100608  (128x786)

    const dim3 blk(256);
    // zero split-K accumulators (w_x, w_decfea, w_gates, w_pga contiguous) + o_dec
    zero_ws<<<385, blk, 0, stream>>>((float4*)ws, (float4*)o_dec);
    // x = [emb, feed] @ W_ic^T + b_ic   (split-K: 8 n-tiles x 8 chunks)
    gemm_mfma<4><<<dim3(8, 8), blk, 0, stream>>>(
        input_emb, W_ic, 1024, 0, input_feed, W_ic, 1024, 512,
        b_ic, w_x, 512, nullptr, nullptr, nullptr, nullptr);
    // gates = x @ W_ih^T + h0 @ W_hh^T + b_ih   (split-K: 32 n-tiles x 4 chunks)
    gemm_mfma<4><<<dim3(32, 4), blk, 0, stream>>>(
        w_x, W_ih, 512, 0, hidden, W_hh, 512, 0,
        b_ih, w_gates, 2048, nullptr, nullptr, nullptr, nullptr);
    // LSTM cell (adds b_hh) -> h1, c1
    lstm_cell<<<256, blk, 0, stream>>>(w_gates, b_hh, context, o_h1, o_c1);
    // dec_fea = h1 @ W_dec^T + b_att   (split-K: 8 x 4)
    gemm_mfma<4><<<dim3(8, 4), blk, 0, stream>>>(
        o_h1, W_dec, 512, 0, nullptr, nullptr, 0, 0,
        b_att, w_decfea, 512, nullptr, nullptr, nullptr, nullptr);
    // attention
    attn_scores<<<12800, blk, 0, stream>>>(sfeat, w_decfea, cov, w_c, v_att, w_e);
    attn_softmax<<<128, blk, 0, stream>>>(w_e, mask, cov, o_attn, o_cov, w_ctx);
    ctx_kernel<<<512, blk, 0, stream>>>(o_attn, states, w_ctx);
    // dec_out = [h1, ctx] @ W_out^T + b_out   (split-K 8 x 8, fused p_gen dot)
    gemm_mfma<4><<<dim3(8, 8), blk, 0, stream>>>(
        o_h1, W_out, 1024, 0, w_ctx, W_out, 1024, 512,
        b_out, o_dec, 512, W_pg, w_pga, nullptr, nullptr);
    // vocab logits + fused per-tile row softmax stats
    gemm_mfma<4><<<dim3(786, 1), blk, 0, stream>>>(
        o_dec, W_v, 512, 0, nullptr, nullptr, 0, 0,
        b_v, w_logits, 50257, nullptr, nullptr, w_pm, w_ps);
    final_write<<<dim3(50, 128), blk, 0, stream>>>(w_logits, w_pm, w_ps, w_pga,
                                                   b_pg, o_final, o_pgen, 786);
    scatter_kernel<<<dim3(2, 128), blk, 0, stream>>>(src_ids, o_attn, o_pgen, o_final);
}